// Round 6
// baseline (489.337 us; speedup 1.0000x reference)
//
#include <hip/hip_runtime.h>

// NLinearMemoryEfficient: out[b,n,o] = sum_i x[b,n,i]*W[n,o,i] + bias[n,o]
// B=8192, N=256, D_IN=64, D_OUT=128, fp32 in/out. bf16 MFMA (thr 7.09e-2).
//
// r6 = wave-independent pipeline (no per-tile barriers).
//  - block = 256 thr (4 waves), one n; wave wv owns rows [wv*256, wv*256+256)
//    of the block's 1024-row slab: 16 tiles x 16 rows. grid = 2048.
//  - W_n staged once as bf16 A-fragments in LDS (16 KB) + ONE __syncthreads.
//    After that waves never sync: vmcnt stalls de-correlate, loads/stores
//    from 12 waves/CU interleave freely.
//  - x fragments loaded DIRECT from global to registers (r2-proven): per
//    lane 4x16B (2 ks x 2 halves) at k = ks*32 + lhi*8; L1 absorbs the
//    half-line double touch. No x LDS, no pack phase, no pack conflicts.
//  - Depth-2 register prefetch: tile j+2 issued in body j (~2 bodies >
//    900 cyc HBM latency).
//  - Full-line store epilogue (r5-proven, fixes r4's 1.6x write
//    amplification): acc -> wave-private patch[16][132] -> 2 rows x 512B
//    contiguous per store instruction (full 128B lines only).
//  - bias as MFMA C operand. C/D layout verified r2-r5:
//    col(lane&15)=b, o = ot*16 + (lane>>4)*4 + reg.

typedef short  short8  __attribute__((ext_vector_type(8)));
typedef float  float4v __attribute__((ext_vector_type(4)));
typedef unsigned int uint4v __attribute__((ext_vector_type(4)));

constexpr int NFEAT = 256;
constexpr int DI    = 64;
constexpr int DO    = 128;
constexpr int TPW   = 16;    // tiles per wave (16 rows each)

__device__ __forceinline__ uint32_t pack_bf16(float a, float b) {
    uint32_t ua = __builtin_bit_cast(uint32_t, a);
    uint32_t ub = __builtin_bit_cast(uint32_t, b);
    ua += 0x7fffu + ((ua >> 16) & 1u);   // RNE
    ub += 0x7fffu + ((ub >> 16) & 1u);
    return (ua >> 16) | (ub & 0xffff0000u);
}

__global__ __launch_bounds__(256, 3) void nlinear_mfma_wi_kernel(
    const float* __restrict__ x, const float* __restrict__ W,
    const float* __restrict__ bias, float* __restrict__ out)
{
    // frag layout: [otile][ks][lane][slot] u32; k = ks*32 + khi*8 + j
    __shared__ __align__(16) uint32_t wfrag[8][2][64][4];   // 16 KB
    __shared__ __align__(16) float    patch[4][16][132];    // 33 KB wave-private

    // XCD-bijective swizzle: 2048 blocks -> 256/XCD -> 32 n per XCD L2.
    const int bid  = blockIdx.x;
    const int swz  = (bid & 7) * 256 + (bid >> 3);
    const int n    = swz >> 3;         // 0..255
    const int slab = swz & 7;          // 8 slabs of 1024 rows

    const int t   = threadIdx.x;
    const int l   = t & 63;
    const int wv  = t >> 6;
    const int llo = l & 15;
    const int lhi = l >> 4;

    // ---- stage W_n as bf16 A-fragments (rows = o), cooperative ----
    const float4* Wn4 = (const float4*)(W + (size_t)n * DO * DI);
#pragma unroll
    for (int p = 0; p < 8; ++p) {
        int idx  = p * 256 + t;              // o = idx>>4, i0 = (t&15)*4
        float4 f = Wn4[idx];
        int lane = (((idx >> 1) & 3) << 4) | (t >> 4);
        int ks   = (idx >> 3) & 1;
        int sp   = (idx & 1) * 2;
        uint2 pk = make_uint2(pack_bf16(f.x, f.y), pack_bf16(f.z, f.w));
        *(uint2*)&wfrag[p][ks][lane][sp] = pk;
    }

    // bias: 4 consecutive o per lane per ot -> C operand of ks=0 MFMA
    float4v bias4[8];
#pragma unroll
    for (int ot = 0; ot < 8; ++ot)
        bias4[ot] = *(const float4v*)&bias[n * DO + ot * 16 + lhi * 4];

    __syncthreads();   // the ONLY block-wide barrier

    const float4* Xg4 = (const float4*)x;
    const uint32_t rw = (uint32_t)slab * 1024u + (uint32_t)wv * 256u;  // wave row 0
    // lane's x base (float4 units): row rw+llo, chunk lhi*2  (+ks*8, +h)
    const uint32_t xbase = ((rw + llo) * NFEAT + (uint32_t)n) * 16u + (uint32_t)lhi * 2u;

    float4 xrA[4], xrB[4];

#define LOADX(J, D)                                                  \
    _Pragma("unroll")                                                \
    for (int q = 0; q < 4; ++q) {   /* q = ks*2 + h */               \
        D[q] = Xg4[xbase + (uint32_t)(J) * 65536u + (q >> 1) * 8u + (q & 1)]; \
    }

    LOADX(0, xrA);
    LOADX(1, xrB);

    for (int j = 0; j < TPW; ++j) {
        float4* cur = (j & 1) ? xrB : xrA;

        // convert tile j to bf16 B-fragments (k = ks*32 + lhi*8 + 0..7)
        uint4v u0 = { pack_bf16(cur[0].x, cur[0].y), pack_bf16(cur[0].z, cur[0].w),
                      pack_bf16(cur[1].x, cur[1].y), pack_bf16(cur[1].z, cur[1].w) };
        uint4v u1 = { pack_bf16(cur[2].x, cur[2].y), pack_bf16(cur[2].z, cur[2].w),
                      pack_bf16(cur[3].x, cur[3].y), pack_bf16(cur[3].z, cur[3].w) };
        short8 xf0 = __builtin_bit_cast(short8, u0);
        short8 xf1 = __builtin_bit_cast(short8, u1);

        if (j + 2 < TPW) { LOADX(j + 2, cur); }   // reuse buffer, 2 bodies ahead

        // ---- compute: D(o,b) = W_n * x^T + bias ----
        float4v acc[8];
#pragma unroll
        for (int ot = 0; ot < 8; ++ot) {
            short8 wf0 = ((const short8*)&wfrag[ot][0][0][0])[l];  // linear, conflict-free
            short8 wf1 = ((const short8*)&wfrag[ot][1][0][0])[l];
            acc[ot] = __builtin_amdgcn_mfma_f32_16x16x32_bf16(wf0, xf0, bias4[ot], 0, 0, 0);
            acc[ot] = __builtin_amdgcn_mfma_f32_16x16x32_bf16(wf1, xf1, acc[ot], 0, 0, 0);
        }

        // ---- full-line store epilogue (wave-private patch, in-order DS) ----
        // acc[ot]: row b = tb + llo (col), o = ot*16 + lhi*4 + reg
#pragma unroll
        for (int ot = 0; ot < 8; ++ot)
            *(float4v*)&patch[wv][llo][ot * 16 + lhi * 4] = acc[ot];

        const uint32_t tb = rw + (uint32_t)j * 16u;
#pragma unroll
        for (int m = 0; m < 8; ++m) {
            int r = m * 2 + (l >> 5);           // 2 rows per instruction
            float4v v = *(const float4v*)&patch[wv][r][(l & 31) * 4];
            uint32_t b = tb + (uint32_t)r;
            // 32 lanes x 16B = 512B contiguous per row: 4 full 128B lines
            *(float4v*)&out[b * 32768u + (uint32_t)n * 128u + (uint32_t)(l & 31) * 4u] = v;
        }
    }
#undef LOADX
}

extern "C" void kernel_launch(void* const* d_in, const int* in_sizes, int n_in,
                              void* d_out, int out_size, void* d_ws, size_t ws_size,
                              hipStream_t stream) {
    const float* xp = (const float*)d_in[0];
    const float* Wp = (const float*)d_in[1];
    const float* bp = (const float*)d_in[2];
    float* op = (float*)d_out;

    dim3 grid(2048);   // 256 n * 8 slabs of 1024 rows
    dim3 block(256);
    hipLaunchKernelGGL(nlinear_mfma_wi_kernel, grid, block, 0, stream, xp, Wp, bp, op);
}

// Round 7
// 410.272 us; speedup vs baseline: 1.1927x; 1.1927x over previous
//
#include <hip/hip_runtime.h>

// NLinearMemoryEfficient: out[b,n,o] = sum_i x[b,n,i]*W[n,o,i] + bias[n,o]
// B=8192, N=256, D_IN=64, D_OUT=128, fp32 in/out. bf16 MFMA (thr 7.09e-2).
//
// r7 = wave-independent + coalesced reads + full-line stores + conflict-free LDS.
//  - block = 256 thr (4 waves), one n; wave wv owns rows [wv*256, +256):
//    16 tiles x 16 rows. grid = 2048. NO per-tile barriers (waves drift).
//  - x tile staged RAW f32 in wave-private LDS [16][68] (pad 68): coalesced
//    global f4 loads (4 rows x 256B per instr), f4 LDS writes, fragment
//    reads, patch writes/reads ALL exactly 8 lanes/4-bank-group (b128 floor).
//  - bf16 conversion AFTER the LDS fragment read (register-side).
//  - Store epilogue through the SAME LDS region (x tile is dead by then;
//    same-wave DS ops are in-order): 4 rows x 256B contiguous per store
//    instruction -> full 128B lines only (r4 proved partial lines cost 1.6x).
//  - Pipeline: LOADX(j+1) issued at body top; DS-write at body bottom
//    (vmcnt naturally waits); ~full body of latency, 16 waves/CU hide rest.
//  - LDS 33.8 KB -> 4 blocks/CU; launch_bounds(256,4) caps VGPR at 128.
//  - A=W frags in shared LDS (16 KB, staged once); C/D layout verified
//    r2-r6: col(lane&15)=b, o = ot*16 + (lane>>4)*4 + reg.

typedef short  short8  __attribute__((ext_vector_type(8)));
typedef float  float4v __attribute__((ext_vector_type(4)));
typedef unsigned int uint4v __attribute__((ext_vector_type(4)));

constexpr int NFEAT = 256;
constexpr int DI    = 64;
constexpr int DO    = 128;
constexpr int TPW   = 16;    // tiles per wave (16 rows each)

__device__ __forceinline__ uint32_t pack_bf16(float a, float b) {
    uint32_t ua = __builtin_bit_cast(uint32_t, a);
    uint32_t ub = __builtin_bit_cast(uint32_t, b);
    ua += 0x7fffu + ((ua >> 16) & 1u);   // RNE
    ub += 0x7fffu + ((ub >> 16) & 1u);
    return (ua >> 16) | (ub & 0xffff0000u);
}

__global__ __launch_bounds__(256, 4) void nlinear_mfma_r7_kernel(
    const float* __restrict__ x, const float* __restrict__ W,
    const float* __restrict__ bias, float* __restrict__ out)
{
    // W A-frags: [otile][ks][lane][slot] u32; k = ks*32 + khi*8 + e
    __shared__ __align__(16) uint32_t wfrag[8][2][64][4];   // 16384 B
    // wave-private x tile / store patch (aliased): rows padded to 68
    __shared__ __align__(16) float    xws[4][16][68];       // 17408 B

    // XCD-bijective swizzle: 2048 blocks -> 256/XCD -> 32 n per XCD L2.
    const int bid  = blockIdx.x;
    const int swz  = (bid & 7) * 256 + (bid >> 3);
    const int n    = swz >> 3;         // 0..255
    const int slab = swz & 7;          // 8 slabs of 1024 rows

    const int t   = threadIdx.x;
    const int l   = t & 63;
    const int wv  = t >> 6;
    const int llo = l & 15;
    const int lhi = l >> 4;

    const float4* Xg4 = (const float4*)x;
    const uint32_t rw = (uint32_t)slab * 1024u + (uint32_t)wv * 256u;

    float4 xr[4];
    // coalesced: instr q reads rows (j*16 + q*4 + lhi), 16 lanes x 16B per row
#define LOADX(J)                                                          \
    _Pragma("unroll")                                                     \
    for (int q = 0; q < 4; ++q)                                           \
        xr[q] = Xg4[((rw + (uint32_t)(J) * 16u + q * 4u + lhi) * NFEAT + n) * 16u + llo];

#define DSWRITE()                                                         \
    _Pragma("unroll")                                                     \
    for (int q = 0; q < 4; ++q)                                           \
        *(float4v*)&xws[wv][q * 4 + lhi][llo * 4] = *(const float4v*)&xr[q];

    LOADX(0);   // start x tile 0 HBM reads first

    // ---- stage W_n as bf16 A-fragments (rows = o), once ----
    const float4* Wn4 = (const float4*)(W + (size_t)n * DO * DI);
#pragma unroll
    for (int p = 0; p < 8; ++p) {
        int idx  = p * 256 + t;              // o = idx>>4, i0 = (idx&15)*4
        float4 f = Wn4[idx];
        int lane = (((idx >> 1) & 3) << 4) | (t >> 4);
        int ks   = (idx >> 3) & 1;
        int sp   = (idx & 1) * 2;
        uint2 pk = make_uint2(pack_bf16(f.x, f.y), pack_bf16(f.z, f.w));
        *(uint2*)&wfrag[p][ks][lane][sp] = pk;
    }

    // bias for epilogue: lane covers o = h*64 + llo*4 .. +3
    float4v bias_e[2];
#pragma unroll
    for (int h = 0; h < 2; ++h)
        bias_e[h] = *(const float4v*)&bias[n * DO + h * 64 + llo * 4];

    __syncthreads();   // the ONLY block-wide barrier (wfrag ready)

    DSWRITE();         // x tile 0 -> wave-private LDS

    const float4v z4 = {0.f, 0.f, 0.f, 0.f};

    for (int j = 0; j < TPW; ++j) {
        if (j + 1 < TPW) { LOADX(j + 1); }   // issue early, consume at bottom

        // ---- fragment read (raw f32) + register-side bf16 pack ----
        // B-frag: col = llo (b-row of tile), k = ks*32 + lhi*8 + e
        float4v xa = *(const float4v*)&xws[wv][llo][lhi * 8];
        float4v xb = *(const float4v*)&xws[wv][llo][lhi * 8 + 4];
        float4v xc = *(const float4v*)&xws[wv][llo][32 + lhi * 8];
        float4v xd = *(const float4v*)&xws[wv][llo][32 + lhi * 8 + 4];
        uint4v u0 = { pack_bf16(xa[0], xa[1]), pack_bf16(xa[2], xa[3]),
                      pack_bf16(xb[0], xb[1]), pack_bf16(xb[2], xb[3]) };
        uint4v u1 = { pack_bf16(xc[0], xc[1]), pack_bf16(xc[2], xc[3]),
                      pack_bf16(xd[0], xd[1]), pack_bf16(xd[2], xd[3]) };
        short8 xf0 = __builtin_bit_cast(short8, u0);
        short8 xf1 = __builtin_bit_cast(short8, u1);

        // ---- compute: D(o,b) = W_n * x^T  (bias added in epilogue) ----
        float4v acc[8];
#pragma unroll
        for (int ot = 0; ot < 8; ++ot) {
            short8 wf0 = ((const short8*)&wfrag[ot][0][0][0])[l];  // b128 floor
            short8 wf1 = ((const short8*)&wfrag[ot][1][0][0])[l];
            acc[ot] = __builtin_amdgcn_mfma_f32_16x16x32_bf16(wf0, xf0, z4, 0, 0, 0);
            acc[ot] = __builtin_amdgcn_mfma_f32_16x16x32_bf16(wf1, xf1, acc[ot], 0, 0, 0);
        }

        // ---- full-line store epilogue through xws (x tile now dead) ----
        // acc[ot][reg]: b = tb + llo, o = ot*16 + lhi*4 + reg
        const uint32_t tb = rw + (uint32_t)j * 16u;
#pragma unroll
        for (int h = 0; h < 2; ++h) {        // two o-halves of 64
#pragma unroll
            for (int o4 = 0; o4 < 4; ++o4)
                *(float4v*)&xws[wv][llo][o4 * 16 + lhi * 4] = acc[h * 4 + o4];
#pragma unroll
            for (int m = 0; m < 4; ++m) {    // 4 rows x 256B contiguous
                float4v v = *(const float4v*)&xws[wv][m * 4 + lhi][llo * 4];
                v += bias_e[h];
                uint32_t b = tb + m * 4u + lhi;
                *(float4v*)&out[b * 32768u + (uint32_t)n * 128u + h * 64u + llo * 4u] = v;
            }
        }

        if (j + 1 < TPW) { DSWRITE(); }      // overwrites patch (dead), in-order
    }
#undef LOADX
#undef DSWRITE
}

extern "C" void kernel_launch(void* const* d_in, const int* in_sizes, int n_in,
                              void* d_out, int out_size, void* d_ws, size_t ws_size,
                              hipStream_t stream) {
    const float* xp = (const float*)d_in[0];
    const float* Wp = (const float*)d_in[1];
    const float* bp = (const float*)d_in[2];
    float* op = (float*)d_out;

    dim3 grid(2048);   // 256 n * 8 slabs of 1024 rows
    dim3 block(256);
    hipLaunchKernelGGL(nlinear_mfma_r7_kernel, grid, block, 0, stream, xp, Wp, bp, op);
}

// Round 8
// 348.046 us; speedup vs baseline: 1.4060x; 1.1788x over previous
//
#include <hip/hip_runtime.h>

// NLinearMemoryEfficient: out[b,n,o] = sum_i x[b,n,i]*W[n,o,i] + bias[n,o]
// B=8192, N=256, D_IN=64, D_OUT=128, fp32 in/out. bf16 MFMA (thr 7.09e-2).
//
// r8 = r5 (best, 346.8us) + conflict-free LDS everywhere. ONE change.
//
// k-permutation freedom: MFMA hardware position k_hw = 8K + 4S + 2m + h
// (K=lane>>4, slot=2S+m, half h) may hold ANY logical k as long as A and B
// use the same map. We choose k_log = 16K + 8S + 4ks + 2m + h, i.e. an f4
// chunk c (= logical k 4c..4c+3) maps to (ks,S,K) = (c&1, (c>>1)&1, c>>2).
// Then a thread's coalesced f4 load becomes ONE uint2 at a thread-constant
// LDS address, and with unit swizzle U' = U ^ ((K&1)<<2) ^ (ks<<1)
// (U = ks*64+K*16+row) the pack writes touch each bank exactly twice
// (minimum) while frag reads stay conflict-free.
// Patch: stride 64 + unit swizzle phys_cu = cu ^ (row&7): write and read
// phases both hit every bank exactly twice (minimum).
//
// Everything else IDENTICAL to r5: block=256 (4 waves, wr x wc = 2x2), one
// n, S=8 tiles of 128 rows, 2 barriers/tile, reg prefetch 1 tile ahead,
// full-line 256B-per-row stores (r4: partial lines cost 1.6x write amp),
// bias as ks=0 MFMA C-operand, XCD-bijective swizzle, LDS 48KB -> 3 blk/CU.

typedef short  short8  __attribute__((ext_vector_type(8)));
typedef float  float4v __attribute__((ext_vector_type(4)));

constexpr int NFEAT  = 256;
constexpr int DI     = 64;
constexpr int DO     = 128;
constexpr int TILE_B = 128;
constexpr int S      = 8;     // tiles per block

__device__ __forceinline__ uint32_t pack_bf16(float a, float b) {
    uint32_t ua = __builtin_bit_cast(uint32_t, a);
    uint32_t ub = __builtin_bit_cast(uint32_t, b);
    ua += 0x7fffu + ((ua >> 16) & 1u);   // RNE
    ub += 0x7fffu + ((ub >> 16) & 1u);
    return (ua >> 16) | (ub & 0xffff0000u);
}

__global__ __launch_bounds__(256, 3) void nlinear_mfma_r8_kernel(
    const float* __restrict__ x, const float* __restrict__ W,
    const float* __restrict__ bias, float* __restrict__ out)
{
    // W A-frags: [otile][ks][lane][slot] u32 (linear; reads conflict-free)
    __shared__ __align__(16) uint32_t wfrag[8][2][64][4];   // 16 KB
    // x B-frags: per tile 128 16B-units, XOR-swizzled placement
    __shared__ __align__(16) uint32_t xfrag[8][512];        // 16 KB
    // store patch: stride 64 + XOR unit swizzle
    __shared__ __align__(16) float    patch[4][16][64];     // 16 KB

    // XCD-bijective swizzle: 2048 blocks -> 256/XCD -> 32 n per XCD L2.
    const int bid  = blockIdx.x;
    const int swz  = (bid & 7) * 256 + (bid >> 3);
    const int n    = swz >> 3;         // 0..255
    const int slab = swz & 7;          // 8 slabs of S*128 = 1024 rows
    const uint32_t b_base = (uint32_t)slab * (TILE_B * S);

    const int t   = threadIdx.x;
    const int l   = t & 63;
    const int wv  = t >> 6;
    const int wr  = wv >> 1;           // b-half (0..1)
    const int wc  = wv & 1;            // o-half (0..1)
    const int llo = l & 15;
    const int lhi = l >> 4;

    // thread-constant pack decomposition: c = t&15 -> (ks,S,K); row r = t>>4
    const int c_ks = t & 1;
    const int c_S  = (t >> 1) & 1;
    const int c_K  = (t >> 2) & 3;
    const int rr   = t >> 4;           // row-in-tile
    const int Upak = ((c_ks << 6) | (c_K << 4) | rr) ^ ((c_K & 1) << 2) ^ (c_ks << 1);
    const int pak_off = Upak * 4 + c_S * 2;   // u32 offset within tile region

    // ---- stage W_n as bf16 A-fragments with the SAME k-permutation ----
    const float4* Wn4 = (const float4*)(W + (size_t)n * DO * DI);
#pragma unroll
    for (int p = 0; p < 8; ++p) {
        int idx  = p * 256 + t;        // o = idx>>4 = p*16 + (t>>4); cw = t&15
        float4 f = Wn4[idx];
        int o    = idx >> 4;
        int lane = (c_K << 4) | (o & 15);
        uint2 pk = make_uint2(pack_bf16(f.x, f.y), pack_bf16(f.z, f.w));
        *(uint2*)&wfrag[o >> 4][c_ks][lane][c_S * 2] = pk;
    }

    // bias: 4 consecutive o per lane -> C operand of ks=0 MFMA
    float4v bias4[4];
#pragma unroll
    for (int ot = 0; ot < 4; ++ot)
        bias4[ot] = *(const float4v*)&bias[n * DO + wc * 64 + ot * 16 + lhi * 4];

    // frag-read base offsets (u32) for the two ks, thread-constant
    const int rd0 = (((0 << 6) | l) ^ (((l >> 4) & 1) << 2) ^ 0) * 4;
    const int rd1 = (((1 << 6) | l) ^ (((l >> 4) & 1) << 2) ^ 2) * 4;

    const float4* Xg4 = (const float4*)x;
    float4 xr[8];

#define LOADX(JT)                                                   \
    _Pragma("unroll")                                               \
    for (int p = 0; p < 8; ++p) {                                   \
        int idx = p * 256 + t;                                      \
        uint32_t b = b_base + (uint32_t)(JT) * TILE_B + (idx >> 4); \
        xr[p] = Xg4[b * 4096u + n * 16u + (idx & 15)];              \
    }

    LOADX(0);

    for (int j = 0; j < S; ++j) {
        __syncthreads();               // xfrag free (prev tile's reads done)

        // pack tile j regs -> swizzled frags (thread-constant addresses,
        // each bank touched exactly twice per instruction)
#pragma unroll
        for (int p = 0; p < 8; ++p) {
            uint2 pk = make_uint2(pack_bf16(xr[p].x, xr[p].y),
                                  pack_bf16(xr[p].z, xr[p].w));
            *(uint2*)&xfrag[p][pak_off] = pk;
        }
        if (j + 1 < S) { LOADX(j + 1); }   // full tile of latency ahead

        __syncthreads();               // xfrag ready

        // ---- compute: D(o,b) = W_n * x^T + bias ----
        float4v acc[4][4];
#pragma unroll
        for (int ks = 0; ks < 2; ++ks) {
            short8 wf[4];
#pragma unroll
            for (int ot = 0; ot < 4; ++ot)
                wf[ot] = *(const short8*)&wfrag[wc * 4 + ot][ks][l][0];
#pragma unroll
            for (int bt = 0; bt < 4; ++bt) {
                short8 xf = *(const short8*)&xfrag[wr * 4 + bt][ks ? rd1 : rd0];
#pragma unroll
                for (int ot = 0; ot < 4; ++ot) {
                    acc[bt][ot] = __builtin_amdgcn_mfma_f32_16x16x32_bf16(
                        wf[ot], xf, (ks == 0) ? bias4[ot] : acc[bt][ot], 0, 0, 0);
                }
            }
        }

        // ---- full-line store epilogue (swizzled patch, conflict-free) ----
        // acc[bt][ot][reg]: row b = ..bt*16+llo, o = wc*64 + ot*16 + lhi*4+reg
#pragma unroll
        for (int bt = 0; bt < 4; ++bt) {
#pragma unroll
            for (int ot = 0; ot < 4; ++ot)
                *(float4v*)&patch[wv][llo][((ot * 4 + lhi) ^ (llo & 7)) * 4] = acc[bt][ot];
            // read row-major: 16 lanes cover one row's 256B (2 full lines)
#pragma unroll
            for (int m = 0; m < 4; ++m) {
                int R = m * 4 + lhi;
                float4v v = *(const float4v*)&patch[wv][R][(llo ^ (R & 7)) * 4];
                uint32_t b = b_base + (uint32_t)j * TILE_B + wr * 64
                           + bt * 16 + (uint32_t)R;
                *(float4v*)&out[b * 32768u + n * 128u + wc * 64u + llo * 4u] = v;
            }
        }
    }
#undef LOADX
}

extern "C" void kernel_launch(void* const* d_in, const int* in_sizes, int n_in,
                              void* d_out, int out_size, void* d_ws, size_t ws_size,
                              hipStream_t stream) {
    const float* xp = (const float*)d_in[0];
    const float* Wp = (const float*)d_in[1];
    const float* bp = (const float*)d_in[2];
    float* op = (float*)d_out;

    dim3 grid(2048);   // 256 n * 8 slabs
    dim3 block(256);
    hipLaunchKernelGGL(nlinear_mfma_r8_kernel, grid, block, 0, stream, xp, Wp, bp, op);
}

// Round 9
// 345.780 us; speedup vs baseline: 1.4152x; 1.0066x over previous
//
#include <hip/hip_runtime.h>

// NLinearMemoryEfficient: out[b,n,o] = sum_i x[b,n,i]*W[n,o,i] + bias[n,o]
// B=8192, N=256, D_IN=64, D_OUT=128, fp32 in/out. bf16 MFMA (thr 7.09e-2).
//
// r9 = r8 (348us, = r5 baseline) + RAW BARRIERS (no vmcnt drain). ONE change.
//
// __syncthreads() makes the compiler emit s_waitcnt vmcnt(0) before
// s_barrier -> every wave drains its 16 epilogue stores + 8 prefetch loads
// at BOTH per-tile barriers (synchronized convoy, 2x/tile). LDS correctness
// only needs lgkmcnt(0) (pack-write visibility); frag reads are consumed by
// MFMAs before the barrier. Raw s_barrier + lgkmcnt-only fence lets stores
// stream across barriers; the compiler's register-dep wait for xr is
// vmcnt(16) (loads issued before the stores), never a full drain.
//
// Everything else IDENTICAL to r8: block=256 (4 waves, wr x wc = 2x2), one
// n, S=8 tiles of 128 rows, reg prefetch 1 tile ahead, k-permuted swizzled
// xfrag pack (conflict-free), full-line 256B-per-row stores via swizzled
// patch (r4: partial lines cost 1.6x write amp), bias as ks=0 MFMA
// C-operand, XCD-bijective swizzle, LDS 48KB -> 3 blk/CU.

typedef short  short8  __attribute__((ext_vector_type(8)));
typedef float  float4v __attribute__((ext_vector_type(4)));

constexpr int NFEAT  = 256;
constexpr int DI     = 64;
constexpr int DO     = 128;
constexpr int TILE_B = 128;
constexpr int S      = 8;     // tiles per block

// raw barrier: LDS-visibility fence only, NO vmcnt drain
#define BAR_LDS()                                                   \
    do {                                                            \
        asm volatile("s_waitcnt lgkmcnt(0)" ::: "memory");          \
        __builtin_amdgcn_s_barrier();                               \
        asm volatile("" ::: "memory");                              \
    } while (0)

__device__ __forceinline__ uint32_t pack_bf16(float a, float b) {
    uint32_t ua = __builtin_bit_cast(uint32_t, a);
    uint32_t ub = __builtin_bit_cast(uint32_t, b);
    ua += 0x7fffu + ((ua >> 16) & 1u);   // RNE
    ub += 0x7fffu + ((ub >> 16) & 1u);
    return (ua >> 16) | (ub & 0xffff0000u);
}

__global__ __launch_bounds__(256, 3) void nlinear_mfma_r9_kernel(
    const float* __restrict__ x, const float* __restrict__ W,
    const float* __restrict__ bias, float* __restrict__ out)
{
    // W A-frags: [otile][ks][lane][slot] u32 (linear; reads conflict-free)
    __shared__ __align__(16) uint32_t wfrag[8][2][64][4];   // 16 KB
    // x B-frags: per tile 128 16B-units, XOR-swizzled placement
    __shared__ __align__(16) uint32_t xfrag[8][512];        // 16 KB
    // store patch: stride 64 + XOR unit swizzle
    __shared__ __align__(16) float    patch[4][16][64];     // 16 KB

    // XCD-bijective swizzle: 2048 blocks -> 256/XCD -> 32 n per XCD L2.
    const int bid  = blockIdx.x;
    const int swz  = (bid & 7) * 256 + (bid >> 3);
    const int n    = swz >> 3;         // 0..255
    const int slab = swz & 7;          // 8 slabs of S*128 = 1024 rows
    const uint32_t b_base = (uint32_t)slab * (TILE_B * S);

    const int t   = threadIdx.x;
    const int l   = t & 63;
    const int wv  = t >> 6;
    const int wr  = wv >> 1;           // b-half (0..1)
    const int wc  = wv & 1;            // o-half (0..1)
    const int llo = l & 15;
    const int lhi = l >> 4;

    // thread-constant pack decomposition: c = t&15 -> (ks,S,K); row r = t>>4
    const int c_ks = t & 1;
    const int c_S  = (t >> 1) & 1;
    const int c_K  = (t >> 2) & 3;
    const int rr   = t >> 4;           // row-in-tile
    const int Upak = ((c_ks << 6) | (c_K << 4) | rr) ^ ((c_K & 1) << 2) ^ (c_ks << 1);
    const int pak_off = Upak * 4 + c_S * 2;   // u32 offset within tile region

    // ---- stage W_n as bf16 A-fragments with the SAME k-permutation ----
    const float4* Wn4 = (const float4*)(W + (size_t)n * DO * DI);
#pragma unroll
    for (int p = 0; p < 8; ++p) {
        int idx  = p * 256 + t;        // o = idx>>4 = p*16 + (t>>4); cw = t&15
        float4 f = Wn4[idx];
        int o    = idx >> 4;
        int lane = (c_K << 4) | (o & 15);
        uint2 pk = make_uint2(pack_bf16(f.x, f.y), pack_bf16(f.z, f.w));
        *(uint2*)&wfrag[o >> 4][c_ks][lane][c_S * 2] = pk;
    }

    // bias: 4 consecutive o per lane -> C operand of ks=0 MFMA
    float4v bias4[4];
#pragma unroll
    for (int ot = 0; ot < 4; ++ot)
        bias4[ot] = *(const float4v*)&bias[n * DO + wc * 64 + ot * 16 + lhi * 4];

    // frag-read base offsets (u32) for the two ks, thread-constant
    const int rd0 = (((0 << 6) | l) ^ (((l >> 4) & 1) << 2) ^ 0) * 4;
    const int rd1 = (((1 << 6) | l) ^ (((l >> 4) & 1) << 2) ^ 2) * 4;

    const float4* Xg4 = (const float4*)x;
    float4 xr[8];

#define LOADX(JT)                                                   \
    _Pragma("unroll")                                               \
    for (int p = 0; p < 8; ++p) {                                   \
        int idx = p * 256 + t;                                      \
        uint32_t b = b_base + (uint32_t)(JT) * TILE_B + (idx >> 4); \
        xr[p] = Xg4[b * 4096u + n * 16u + (idx & 15)];              \
    }

    LOADX(0);

    for (int j = 0; j < S; ++j) {
        BAR_LDS();                     // xfrag free (prev tile's reads consumed)

        // pack tile j regs -> swizzled frags (thread-constant addresses,
        // each bank touched exactly twice per instruction)
#pragma unroll
        for (int p = 0; p < 8; ++p) {
            uint2 pk = make_uint2(pack_bf16(xr[p].x, xr[p].y),
                                  pack_bf16(xr[p].z, xr[p].w));
            *(uint2*)&xfrag[p][pak_off] = pk;
        }
        if (j + 1 < S) { LOADX(j + 1); }   // full tile of latency ahead

        BAR_LDS();                     // xfrag ready (lgkmcnt(0) before bar)

        // ---- compute: D(o,b) = W_n * x^T + bias ----
        float4v acc[4][4];
#pragma unroll
        for (int ks = 0; ks < 2; ++ks) {
            short8 wf[4];
#pragma unroll
            for (int ot = 0; ot < 4; ++ot)
                wf[ot] = *(const short8*)&wfrag[wc * 4 + ot][ks][l][0];
#pragma unroll
            for (int bt = 0; bt < 4; ++bt) {
                short8 xf = *(const short8*)&xfrag[wr * 4 + bt][ks ? rd1 : rd0];
#pragma unroll
                for (int ot = 0; ot < 4; ++ot) {
                    acc[bt][ot] = __builtin_amdgcn_mfma_f32_16x16x32_bf16(
                        wf[ot], xf, (ks == 0) ? bias4[ot] : acc[bt][ot], 0, 0, 0);
                }
            }
        }

        // ---- full-line store epilogue (swizzled patch, conflict-free) ----
        // acc[bt][ot][reg]: row b = ..bt*16+llo, o = wc*64 + ot*16 + lhi*4+reg
#pragma unroll
        for (int bt = 0; bt < 4; ++bt) {
#pragma unroll
            for (int ot = 0; ot < 4; ++ot)
                *(float4v*)&patch[wv][llo][((ot * 4 + lhi) ^ (llo & 7)) * 4] = acc[bt][ot];
            // read row-major: 16 lanes cover one row's 256B (2 full lines)
#pragma unroll
            for (int m = 0; m < 4; ++m) {
                int R = m * 4 + lhi;
                float4v v = *(const float4v*)&patch[wv][R][(llo ^ (R & 7)) * 4];
                uint32_t b = b_base + (uint32_t)j * TILE_B + wr * 64
                           + bt * 16 + (uint32_t)R;
                *(float4v*)&out[b * 32768u + n * 128u + wc * 64u + llo * 4u] = v;
            }
        }
    }
#undef LOADX
}

extern "C" void kernel_launch(void* const* d_in, const int* in_sizes, int n_in,
                              void* d_out, int out_size, void* d_ws, size_t ws_size,
                              hipStream_t stream) {
    const float* xp = (const float*)d_in[0];
    const float* Wp = (const float*)d_in[1];
    const float* bp = (const float*)d_in[2];
    float* op = (float*)d_out;

    dim3 grid(2048);   // 256 n * 8 slabs
    dim3 block(256);
    hipLaunchKernelGGL(nlinear_mfma_r9_kernel, grid, block, 0, stream, xp, Wp, bp, op);
}

// Round 10
// 317.273 us; speedup vs baseline: 1.5423x; 1.0898x over previous
//
#include <hip/hip_runtime.h>

// NLinearMemoryEfficient: out[b,n,o] = sum_i x[b,n,i]*W[n,o,i] + bias[n,o]
// B=8192, N=256, D_IN=64, D_OUT=128, fp32 in/out. bf16 MFMA (thr 7.09e-2).
//
// r10 = r9 + DISPATCH-ORDER SWIZZLE ONLY (n fastest).
//
// r5/r8/r9 (3 different stall structures) all = 346-348us -> limiter is the
// memory system's rate for the CONCURRENT request mix, not intra-kernel
// stalls. Old order: slab fastest per XCD -> resident blocks touch few n
// columns (256B/512B) of each 64/128KB b-row -> sparse DRAM page touches.
// New order: n = bid&255 varies fastest -> ~768 resident blocks cover ALL
// 256 n of ~3 slabs -> reads/writes densely tile complete b-rows ->
// streaming-like DRAM page locality. Blocks sharing W_n are 256 apart ->
// same XCD (bid%8 preserved) -> W_n L2-local.
//
// Everything else IDENTICAL to r9: block=256 (4 waves, wr x wc = 2x2), one
// n, S=8 tiles of 128 rows, raw lgkmcnt-only barriers (stores stream across
// them), reg prefetch 1 tile ahead, k-permuted swizzled xfrag pack
// (conflict-free), full-line 256B-per-row stores via swizzled patch (r4:
// partial lines cost 1.6x write amp), bias as ks=0 MFMA C-operand,
// LDS 48KB -> 3 blk/CU.

typedef short  short8  __attribute__((ext_vector_type(8)));
typedef float  float4v __attribute__((ext_vector_type(4)));

constexpr int NFEAT  = 256;
constexpr int DI     = 64;
constexpr int DO     = 128;
constexpr int TILE_B = 128;
constexpr int S      = 8;     // tiles per block

// raw barrier: LDS-visibility fence only, NO vmcnt drain
#define BAR_LDS()                                                   \
    do {                                                            \
        asm volatile("s_waitcnt lgkmcnt(0)" ::: "memory");          \
        __builtin_amdgcn_s_barrier();                               \
        asm volatile("" ::: "memory");                              \
    } while (0)

__device__ __forceinline__ uint32_t pack_bf16(float a, float b) {
    uint32_t ua = __builtin_bit_cast(uint32_t, a);
    uint32_t ub = __builtin_bit_cast(uint32_t, b);
    ua += 0x7fffu + ((ua >> 16) & 1u);   // RNE
    ub += 0x7fffu + ((ub >> 16) & 1u);
    return (ua >> 16) | (ub & 0xffff0000u);
}

__global__ __launch_bounds__(256, 3) void nlinear_mfma_r10_kernel(
    const float* __restrict__ x, const float* __restrict__ W,
    const float* __restrict__ bias, float* __restrict__ out)
{
    // W A-frags: [otile][ks][lane][slot] u32 (linear; reads conflict-free)
    __shared__ __align__(16) uint32_t wfrag[8][2][64][4];   // 16 KB
    // x B-frags: per tile 128 16B-units, XOR-swizzled placement
    __shared__ __align__(16) uint32_t xfrag[8][512];        // 16 KB
    // store patch: stride 64 + XOR unit swizzle
    __shared__ __align__(16) float    patch[4][16][64];     // 16 KB

    // n fastest in dispatch order: resident set covers all n of ~3 slabs.
    const int bid  = blockIdx.x;
    const int n    = bid & 255;        // 0..255, varies fastest
    const int slab = bid >> 8;         // 8 slabs of S*128 = 1024 rows
    const uint32_t b_base = (uint32_t)slab * (TILE_B * S);

    const int t   = threadIdx.x;
    const int l   = t & 63;
    const int wv  = t >> 6;
    const int wr  = wv >> 1;           // b-half (0..1)
    const int wc  = wv & 1;            // o-half (0..1)
    const int llo = l & 15;
    const int lhi = l >> 4;

    // thread-constant pack decomposition: c = t&15 -> (ks,S,K); row r = t>>4
    const int c_ks = t & 1;
    const int c_S  = (t >> 1) & 1;
    const int c_K  = (t >> 2) & 3;
    const int rr   = t >> 4;           // row-in-tile
    const int Upak = ((c_ks << 6) | (c_K << 4) | rr) ^ ((c_K & 1) << 2) ^ (c_ks << 1);
    const int pak_off = Upak * 4 + c_S * 2;   // u32 offset within tile region

    // ---- stage W_n as bf16 A-fragments with the SAME k-permutation ----
    const float4* Wn4 = (const float4*)(W + (size_t)n * DO * DI);
#pragma unroll
    for (int p = 0; p < 8; ++p) {
        int idx  = p * 256 + t;        // o = idx>>4 = p*16 + (t>>4); cw = t&15
        float4 f = Wn4[idx];
        int o    = idx >> 4;
        int lane = (c_K << 4) | (o & 15);
        uint2 pk = make_uint2(pack_bf16(f.x, f.y), pack_bf16(f.z, f.w));
        *(uint2*)&wfrag[o >> 4][c_ks][lane][c_S * 2] = pk;
    }

    // bias: 4 consecutive o per lane -> C operand of ks=0 MFMA
    float4v bias4[4];
#pragma unroll
    for (int ot = 0; ot < 4; ++ot)
        bias4[ot] = *(const float4v*)&bias[n * DO + wc * 64 + ot * 16 + lhi * 4];

    // frag-read base offsets (u32) for the two ks, thread-constant
    const int rd0 = (((0 << 6) | l) ^ (((l >> 4) & 1) << 2) ^ 0) * 4;
    const int rd1 = (((1 << 6) | l) ^ (((l >> 4) & 1) << 2) ^ 2) * 4;

    const float4* Xg4 = (const float4*)x;
    float4 xr[8];

#define LOADX(JT)                                                   \
    _Pragma("unroll")                                               \
    for (int p = 0; p < 8; ++p) {                                   \
        int idx = p * 256 + t;                                      \
        uint32_t b = b_base + (uint32_t)(JT) * TILE_B + (idx >> 4); \
        xr[p] = Xg4[b * 4096u + n * 16u + (idx & 15)];              \
    }

    LOADX(0);

    for (int j = 0; j < S; ++j) {
        BAR_LDS();                     // xfrag free (prev tile's reads consumed)

        // pack tile j regs -> swizzled frags (thread-constant addresses,
        // each bank touched exactly twice per instruction)
#pragma unroll
        for (int p = 0; p < 8; ++p) {
            uint2 pk = make_uint2(pack_bf16(xr[p].x, xr[p].y),
                                  pack_bf16(xr[p].z, xr[p].w));
            *(uint2*)&xfrag[p][pak_off] = pk;
        }
        if (j + 1 < S) { LOADX(j + 1); }   // full tile of latency ahead

        BAR_LDS();                     // xfrag ready (lgkmcnt(0) before bar)

        // ---- compute: D(o,b) = W_n * x^T + bias ----
        float4v acc[4][4];
#pragma unroll
        for (int ks = 0; ks < 2; ++ks) {
            short8 wf[4];
#pragma unroll
            for (int ot = 0; ot < 4; ++ot)
                wf[ot] = *(const short8*)&wfrag[wc * 4 + ot][ks][l][0];
#pragma unroll
            for (int bt = 0; bt < 4; ++bt) {
                short8 xf = *(const short8*)&xfrag[wr * 4 + bt][ks ? rd1 : rd0];
#pragma unroll
                for (int ot = 0; ot < 4; ++ot) {
                    acc[bt][ot] = __builtin_amdgcn_mfma_f32_16x16x32_bf16(
                        wf[ot], xf, (ks == 0) ? bias4[ot] : acc[bt][ot], 0, 0, 0);
                }
            }
        }

        // ---- full-line store epilogue (swizzled patch, conflict-free) ----
        // acc[bt][ot][reg]: row b = ..bt*16+llo, o = wc*64 + ot*16 + lhi*4+reg
#pragma unroll
        for (int bt = 0; bt < 4; ++bt) {
#pragma unroll
            for (int ot = 0; ot < 4; ++ot)
                *(float4v*)&patch[wv][llo][((ot * 4 + lhi) ^ (llo & 7)) * 4] = acc[bt][ot];
            // read row-major: 16 lanes cover one row's 256B (2 full lines)
#pragma unroll
            for (int m = 0; m < 4; ++m) {
                int R = m * 4 + lhi;
                float4v v = *(const float4v*)&patch[wv][R][(llo ^ (R & 7)) * 4];
                uint32_t b = b_base + (uint32_t)j * TILE_B + wr * 64
                           + bt * 16 + (uint32_t)R;
                *(float4v*)&out[b * 32768u + n * 128u + wc * 64u + llo * 4u] = v;
            }
        }
    }
#undef LOADX
}

extern "C" void kernel_launch(void* const* d_in, const int* in_sizes, int n_in,
                              void* d_out, int out_size, void* d_ws, size_t ws_size,
                              hipStream_t stream) {
    const float* xp = (const float*)d_in[0];
    const float* Wp = (const float*)d_in[1];
    const float* bp = (const float*)d_in[2];
    float* op = (float*)d_out;

    dim3 grid(2048);   // 256 n (fastest) * 8 slabs
    dim3 block(256);
    hipLaunchKernelGGL(nlinear_mfma_r10_kernel, grid, block, 0, stream, xp, Wp, bp, op);
}

// Round 11
// 310.572 us; speedup vs baseline: 1.5756x; 1.0216x over previous
//
#include <hip/hip_runtime.h>

// NLinearMemoryEfficient: out[b,n,o] = sum_i x[b,n,i]*W[n,o,i] + bias[n,o]
// B=8192, N=256, D_IN=64, D_OUT=128, fp32 in/out. bf16 MFMA (thr 7.09e-2).
//
// r11 = r10 (317us) + NONTEMPORAL streaming hints ONLY.
//
// Both big streams are touch-once (x lines read once by one block; out
// written once, never read) -> route them around the L2/L3 fill+evict
// pipeline with nt loads/stores. W/bias keep the cached path (cross-block
// reuse). Pre-committed contract: neutral result => practical roofline.
//
// Everything else IDENTICAL to r10: n-fastest dispatch order (DRAM page
// locality of the concurrent mix - the r10 +9% win), block=256 (4 waves,
// wr x wc = 2x2), one n, S=8 tiles of 128 rows, raw lgkmcnt-only barriers,
// reg prefetch 1 tile ahead, k-permuted swizzled xfrag pack (conflict-
// free), full-line 256B-per-row stores via swizzled patch (r4: partial
// lines cost 1.6x write amp), bias as ks=0 MFMA C-operand, LDS 48KB.

typedef short  short8  __attribute__((ext_vector_type(8)));
typedef float  float4v __attribute__((ext_vector_type(4)));

constexpr int NFEAT  = 256;
constexpr int DI     = 64;
constexpr int DO     = 128;
constexpr int TILE_B = 128;
constexpr int S      = 8;     // tiles per block

// raw barrier: LDS-visibility fence only, NO vmcnt drain
#define BAR_LDS()                                                   \
    do {                                                            \
        asm volatile("s_waitcnt lgkmcnt(0)" ::: "memory");          \
        __builtin_amdgcn_s_barrier();                               \
        asm volatile("" ::: "memory");                              \
    } while (0)

__device__ __forceinline__ uint32_t pack_bf16(float a, float b) {
    uint32_t ua = __builtin_bit_cast(uint32_t, a);
    uint32_t ub = __builtin_bit_cast(uint32_t, b);
    ua += 0x7fffu + ((ua >> 16) & 1u);   // RNE
    ub += 0x7fffu + ((ub >> 16) & 1u);
    return (ua >> 16) | (ub & 0xffff0000u);
}

__global__ __launch_bounds__(256, 3) void nlinear_mfma_r11_kernel(
    const float* __restrict__ x, const float* __restrict__ W,
    const float* __restrict__ bias, float* __restrict__ out)
{
    // W A-frags: [otile][ks][lane][slot] u32 (linear; reads conflict-free)
    __shared__ __align__(16) uint32_t wfrag[8][2][64][4];   // 16 KB
    // x B-frags: per tile 128 16B-units, XOR-swizzled placement
    __shared__ __align__(16) uint32_t xfrag[8][512];        // 16 KB
    // store patch: stride 64 + XOR unit swizzle
    __shared__ __align__(16) float    patch[4][16][64];     // 16 KB

    // n fastest in dispatch order: resident set covers all n of ~3 slabs.
    const int bid  = blockIdx.x;
    const int n    = bid & 255;        // 0..255, varies fastest
    const int slab = bid >> 8;         // 8 slabs of S*128 = 1024 rows
    const uint32_t b_base = (uint32_t)slab * (TILE_B * S);

    const int t   = threadIdx.x;
    const int l   = t & 63;
    const int wv  = t >> 6;
    const int wr  = wv >> 1;           // b-half (0..1)
    const int wc  = wv & 1;            // o-half (0..1)
    const int llo = l & 15;
    const int lhi = l >> 4;

    // thread-constant pack decomposition: c = t&15 -> (ks,S,K); row r = t>>4
    const int c_ks = t & 1;
    const int c_S  = (t >> 1) & 1;
    const int c_K  = (t >> 2) & 3;
    const int rr   = t >> 4;           // row-in-tile
    const int Upak = ((c_ks << 6) | (c_K << 4) | rr) ^ ((c_K & 1) << 2) ^ (c_ks << 1);
    const int pak_off = Upak * 4 + c_S * 2;   // u32 offset within tile region

    // ---- stage W_n as bf16 A-fragments with the SAME k-permutation ----
    const float4* Wn4 = (const float4*)(W + (size_t)n * DO * DI);
#pragma unroll
    for (int p = 0; p < 8; ++p) {
        int idx  = p * 256 + t;        // o = idx>>4 = p*16 + (t>>4); cw = t&15
        float4 f = Wn4[idx];
        int o    = idx >> 4;
        int lane = (c_K << 4) | (o & 15);
        uint2 pk = make_uint2(pack_bf16(f.x, f.y), pack_bf16(f.z, f.w));
        *(uint2*)&wfrag[o >> 4][c_ks][lane][c_S * 2] = pk;
    }

    // bias: 4 consecutive o per lane -> C operand of ks=0 MFMA
    float4v bias4[4];
#pragma unroll
    for (int ot = 0; ot < 4; ++ot)
        bias4[ot] = *(const float4v*)&bias[n * DO + wc * 64 + ot * 16 + lhi * 4];

    // frag-read base offsets (u32) for the two ks, thread-constant
    const int rd0 = (((0 << 6) | l) ^ (((l >> 4) & 1) << 2) ^ 0) * 4;
    const int rd1 = (((1 << 6) | l) ^ (((l >> 4) & 1) << 2) ^ 2) * 4;

    const float4v* Xg4 = (const float4v*)x;
    float4v xr[8];

#define LOADX(JT)                                                   \
    _Pragma("unroll")                                               \
    for (int p = 0; p < 8; ++p) {                                   \
        int idx = p * 256 + t;                                      \
        uint32_t b = b_base + (uint32_t)(JT) * TILE_B + (idx >> 4); \
        xr[p] = __builtin_nontemporal_load(                         \
                    &Xg4[b * 4096u + n * 16u + (idx & 15)]);        \
    }

    LOADX(0);

    for (int j = 0; j < S; ++j) {
        BAR_LDS();                     // xfrag free (prev tile's reads consumed)

        // pack tile j regs -> swizzled frags (thread-constant addresses,
        // each bank touched exactly twice per instruction)
#pragma unroll
        for (int p = 0; p < 8; ++p) {
            uint2 pk = make_uint2(pack_bf16(xr[p][0], xr[p][1]),
                                  pack_bf16(xr[p][2], xr[p][3]));
            *(uint2*)&xfrag[p][pak_off] = pk;
        }
        if (j + 1 < S) { LOADX(j + 1); }   // full tile of latency ahead

        BAR_LDS();                     // xfrag ready (lgkmcnt(0) before bar)

        // ---- compute: D(o,b) = W_n * x^T + bias ----
        float4v acc[4][4];
#pragma unroll
        for (int ks = 0; ks < 2; ++ks) {
            short8 wf[4];
#pragma unroll
            for (int ot = 0; ot < 4; ++ot)
                wf[ot] = *(const short8*)&wfrag[wc * 4 + ot][ks][l][0];
#pragma unroll
            for (int bt = 0; bt < 4; ++bt) {
                short8 xf = *(const short8*)&xfrag[wr * 4 + bt][ks ? rd1 : rd0];
#pragma unroll
                for (int ot = 0; ot < 4; ++ot) {
                    acc[bt][ot] = __builtin_amdgcn_mfma_f32_16x16x32_bf16(
                        wf[ot], xf, (ks == 0) ? bias4[ot] : acc[bt][ot], 0, 0, 0);
                }
            }
        }

        // ---- full-line store epilogue (swizzled patch, conflict-free) ----
        // acc[bt][ot][reg]: row b = ..bt*16+llo, o = wc*64 + ot*16 + lhi*4+reg
#pragma unroll
        for (int bt = 0; bt < 4; ++bt) {
#pragma unroll
            for (int ot = 0; ot < 4; ++ot)
                *(float4v*)&patch[wv][llo][((ot * 4 + lhi) ^ (llo & 7)) * 4] = acc[bt][ot];
            // read row-major: 16 lanes cover one row's 256B (2 full lines)
#pragma unroll
            for (int m = 0; m < 4; ++m) {
                int R = m * 4 + lhi;
                float4v v = *(const float4v*)&patch[wv][R][(llo ^ (R & 7)) * 4];
                uint32_t b = b_base + (uint32_t)j * TILE_B + wr * 64
                           + bt * 16 + (uint32_t)R;
                __builtin_nontemporal_store(
                    v, (float4v*)&out[b * 32768u + n * 128u + wc * 64u + llo * 4u]);
            }
        }
    }
#undef LOADX
}

extern "C" void kernel_launch(void* const* d_in, const int* in_sizes, int n_in,
                              void* d_out, int out_size, void* d_ws, size_t ws_size,
                              hipStream_t stream) {
    const float* xp = (const float*)d_in[0];
    const float* Wp = (const float*)d_in[1];
    const float* bp = (const float*)d_in[2];
    float* op = (float*)d_out;

    dim3 grid(2048);   // 256 n (fastest) * 8 slabs
    dim3 block(256);
    hipLaunchKernelGGL(nlinear_mfma_r11_kernel, grid, block, 0, stream, xp, Wp, bp, op);
}